// Round 10
// baseline (433.753 us; speedup 1.0000x reference)
//
#include <hip/hip_runtime.h>
#include <hip/hip_bf16.h>
#include <math.h>

// STAttentionBlock  N=32 C=64 T=400 V=27 S=2 IC=16 — f32 I/O.
// Round 13: y2 stored TRANSPOSED y2T[n][pixel][c] by stage1 (uint2 stores);
// k_stage2 loses its LDS staging entirely — B-fragments and residual are
// direct global vector loads from y2T (zero LDS, launch_bounds(256,8)).
// stage1 = round-12 8-wave MFMA (verified) with new ff-write only.
// k_scores = round 7.

typedef __hip_bfloat16 bf16;
typedef unsigned short u16t;
typedef unsigned int u32t;

using bf16x8 = __attribute__((ext_vector_type(8))) short;
using f32x4  = __attribute__((ext_vector_type(4))) float;

#define NN 32
#define CH 64
#define TT 400
#define VV 27
#define PIX 10800            // T*V
#define NSUV (32*2*27*27)    // 46656
#define XTOT (NN*CH*PIX)     // 22118400

#define TB1 4                // t per block, stage1 (112 pixels = 7 tiles of 16)
#define NT1 100
#define TB2 4                // t per block, stage2 (MFMA)
#define NT2 100
#define TBS 9                // t per block, scores
#define NTS 45

__device__ __forceinline__ float lrelu(float x) { return x >= 0.f ? x : 0.1f * x; }
__device__ __forceinline__ float4 ld4(const float* p) { return *reinterpret_cast<const float4*>(p); }
__device__ __forceinline__ uint2 ld2u(const u32t* p) { return *reinterpret_cast<const uint2*>(p); }

// packed bf16 helpers
__device__ __forceinline__ u16t f2bf(float f) {
    return __bfloat16_as_ushort(__float2bfloat16(f));
}
__device__ __forceinline__ u32t packbf(float lo, float hi) {
    return ((u32t)f2bf(hi) << 16) | (u32t)f2bf(lo);
}
__device__ __forceinline__ float bf2f(u16t u) {
    return __uint_as_float(((u32t)u) << 16);
}
__device__ __forceinline__ u32t cvtpk(float lo, float hi) {
    u32t r;
    asm("v_cvt_pk_bf16_f32 %0, %1, %2" : "=v"(r) : "v"(lo), "v"(hi));
    return r;
}
// c += a.lo*b.lo + a.hi*b.hi  (bf16 pairs, f32 accum)
__device__ __forceinline__ void dot2v(float& c, u32t a, u32t b) {
    asm("v_dot2_f32_bf16 %0, %1, %2, %0" : "+v"(c) : "v"(a), "v"(b));
}
__device__ __forceinline__ void dot2s(float& c, u32t a_sgpr, u32t b) {
    asm("v_dot2_f32_bf16 %0, %1, %2, %0" : "+v"(c) : "s"(a_sgpr), "v"(b));
}

// ---------------------------------------------------------------------------
// k_prep: BN-folded weights.
//   wfoA[o*128+j]        bf16 row-major (j = s*64+c)   conv_outs A-operand
//   wffA[o*64+c]         bf16 row-major                ff A-operand
//   wtA [o*192+kt*64+c]  bf16 row-major (k' kt-major)  tconv A-operand
//   wqkpk[(sq*16+c)*32+cc2] u32 pairs                  scores proj
//   bfo/bff/bft[o] = b*inv + beta
// ---------------------------------------------------------------------------
__global__ void k_prep(
    const float* __restrict__ w_outs, const float* __restrict__ b_outs,
    const float* __restrict__ go, const float* __restrict__ bo,
    const float* __restrict__ mo, const float* __restrict__ vo,
    const float* __restrict__ w_ff, const float* __restrict__ b_ff,
    const float* __restrict__ gf, const float* __restrict__ bf,
    const float* __restrict__ mf, const float* __restrict__ vf,
    const float* __restrict__ w_t, const float* __restrict__ b_t,
    const float* __restrict__ gt, const float* __restrict__ btb,
    const float* __restrict__ mt, const float* __restrict__ vt,
    const float* __restrict__ w_in,
    u16t* __restrict__ wfoA, float* __restrict__ bfo,
    u16t* __restrict__ wffA, float* __restrict__ bff,
    u16t* __restrict__ wtA, float* __restrict__ bft,
    u32t* __restrict__ wqkpk)
{
    const int total = 8192 + 4096 + 12288 + 192 + 2048;
    for (int idx = blockIdx.x * 256 + threadIdx.x; idx < total; idx += gridDim.x * 256) {
        if (idx < 8192) {
            int o = idx >> 7, j = idx & 127;
            float inv = go[o] * rsqrtf(vo[o] + 1e-5f);
            wfoA[idx] = f2bf(w_outs[o * 128 + j] * inv);
        } else if (idx < 12288) {
            int r = idx - 8192; int o = r >> 6, c = r & 63;
            float inv = gf[o] * rsqrtf(vf[o] + 1e-5f);
            wffA[r] = f2bf(w_ff[o * 64 + c] * inv);
        } else if (idx < 24576) {
            int r = idx - 12288;                  // r = o*192 + kt*64 + c
            int o = r / 192, k2 = r % 192;
            int kt = k2 >> 6, c = k2 & 63;
            float inv = gt[o] * rsqrtf(vt[o] + 1e-5f);
            wtA[r] = f2bf(w_t[o * 192 + c * 3 + kt] * inv);
        } else if (idx < 24768) {
            int r = idx - 24576; int o = r & 63, which = r >> 6;
            if (which == 0) {
                float inv = go[o] * rsqrtf(vo[o] + 1e-5f);
                bfo[o] = b_outs[o] * inv + bo[o] - mo[o] * inv;
            } else if (which == 1) {
                float inv = gf[o] * rsqrtf(vf[o] + 1e-5f);
                bff[o] = b_ff[o] * inv + bf[o] - mf[o] * inv;
            } else {
                float inv = gt[o] * rsqrtf(vt[o] + 1e-5f);
                bft[o] = b_t[o] * inv + btb[o] - mt[o] * inv;
            }
        } else {
            int i = idx - 24768;                 // i < 2048
            int cc2 = i & 31, c = (i >> 5) & 15, sq = i >> 9;
            int s = sq >> 1, qk = sq & 1;
            int row = qk * 32 + s * 16 + c;
            wqkpk[i] = packbf(w_in[row * 64 + 2 * cc2], w_in[row * 64 + 2 * cc2 + 1]);
        }
    }
}

// ---------------------------------------------------------------------------
// k_pbias: pb[s*2+qk][c][u28] = b_in + sum_cc w_in * pe[cc][u]  (PE absorbed)
// ---------------------------------------------------------------------------
__global__ __launch_bounds__(256) void k_pbias(
    const float* __restrict__ w_in, const float* __restrict__ b_in,
    float* __restrict__ pb)
{
    __shared__ float pe[64 * 27];
    const int tid = threadIdx.x;
    for (int idx = tid; idx < 1728; idx += 256) {
        int c = idx / 27, u = idx % 27;
        float div = expf(-0.28782313662425575f * (float)(c >> 1));
        float ang = div * (float)u;
        pe[idx] = (c & 1) ? cosf(ang) : sinf(ang);
    }
    __syncthreads();
    for (int idx = tid; idx < 1792; idx += 256) {
        int u = idx % 28, r = idx / 28;
        int c = r % 16, sq = r / 16;
        if (u >= 27) { pb[idx] = 0.f; continue; }
        int s = sq >> 1, qk = sq & 1;
        int row = qk * 32 + s * 16 + c;
        float acc = b_in[row];
        for (int cc = 0; cc < 64; ++cc) acc += w_in[row * 64 + cc] * pe[cc * 27 + u];
        pb[idx] = acc;
    }
}

// ---------------------------------------------------------------------------
// k_scores: grid (45 tchunks, 2 s, 32 n). Lane = pixel (tt,u). (round 7)
// ---------------------------------------------------------------------------
__global__ __launch_bounds__(256, 4) void k_scores(
    const float* __restrict__ x, const u32t* __restrict__ wqkpk,
    const float* __restrict__ pb, float* __restrict__ scores)
{
    const int tid = threadIdx.x;
    const int s = blockIdx.y, n = blockIdx.z;
    const int t0 = blockIdx.x * TBS;

    __shared__ u32t qlds[TBS * 27 * 10];
    __shared__ u32t klds[TBS * 27 * 10];

    const int pcl = tid < 243 ? tid : 242;
    const int tt = pcl / 27, u = pcl - tt * 27;
    const int t = t0 + tt;
    const bool valid = (tid < 243) && (t < TT);

    u32t xp[32];
    const float* xb = x + (size_t)n * 64 * PIX + (size_t)(t < TT ? t : 0) * 27 + u;
    #pragma unroll
    for (int c2 = 0; c2 < 32; ++c2) {
        float v0 = xb[(size_t)(2 * c2) * PIX];
        float v1 = xb[(size_t)(2 * c2 + 1) * PIX];
        xp[c2] = cvtpk(v0, v1);
    }

    const float* pbq = pb + ((s * 2 + 0) * 16) * 28 + u;
    const float* pbk = pb + ((s * 2 + 1) * 16) * 28 + u;
    const u32t* wq = wqkpk + (s * 2 + 0) * 16 * 32;
    const u32t* wk = wqkpk + (s * 2 + 1) * 16 * 32;
    float qr[16], kr[16];
    #pragma unroll
    for (int c = 0; c < 16; ++c) { qr[c] = pbq[c * 28]; kr[c] = pbk[c * 28]; }
    #pragma unroll
    for (int c = 0; c < 16; ++c) {
        const u32t* wr = wq + c * 32;
        #pragma unroll
        for (int c2 = 0; c2 < 32; ++c2) dot2s(qr[c], wr[c2], xp[c2]);
    }
    #pragma unroll
    for (int c = 0; c < 16; ++c) {
        const u32t* wr = wk + c * 32;
        #pragma unroll
        for (int c2 = 0; c2 < 32; ++c2) dot2s(kr[c], wr[c2], xp[c2]);
    }

    if (tid < 243) {
        #pragma unroll
        for (int c2 = 0; c2 < 8; ++c2) {
            qlds[(tt * 27 + u) * 10 + c2] = valid ? cvtpk(qr[2 * c2], qr[2 * c2 + 1]) : 0u;
            klds[(tt * 27 + u) * 10 + c2] = valid ? cvtpk(kr[2 * c2], kr[2 * c2 + 1]) : 0u;
        }
    }
    __syncthreads();

    const int sid = tid < 243 ? tid : 242;
    const int ug = sid / 9, vg = sid % 9;
    const int v0 = vg * 3;
    float sc0 = 0.f, sc1 = 0.f, sc2 = 0.f;
    for (int t2 = 0; t2 < TBS; ++t2) {
        const u32t* qrow = qlds + (t2 * 27 + ug) * 10;
        const u32t* k0 = klds + (t2 * 27 + v0) * 10;
        #pragma unroll
        for (int c4 = 0; c4 < 4; ++c4) {
            uint2 qp = ld2u(qrow + c4 * 2);
            uint2 ka = ld2u(k0 + c4 * 2);
            uint2 kb = ld2u(k0 + 10 + c4 * 2);
            uint2 kc = ld2u(k0 + 20 + c4 * 2);
            dot2v(sc0, qp.x, ka.x); dot2v(sc0, qp.y, ka.y);
            dot2v(sc1, qp.x, kb.x); dot2v(sc1, qp.y, kb.y);
            dot2v(sc2, qp.x, kc.x); dot2v(sc2, qp.y, kc.y);
        }
    }
    if (tid < 243) {
        float* sb = scores + (n * 2 + s) * 729 + ug * 27 + v0;
        atomicAdd(&sb[0], sc0);
        atomicAdd(&sb[1], sc1);
        atomicAdd(&sb[2], sc2);
    }
}

// ---------------------------------------------------------------------------
// k_att: attTp[((n*2+s)*32+v)*16+e] = pack_bf16(att(2e,v), att(2e+1,v)),
// v-rows 27..31 zero (MFMA B-operand padding).
// ---------------------------------------------------------------------------
__global__ void k_att(const float* __restrict__ scores,
                      const float* __restrict__ alphas,
                      const float* __restrict__ att0,
                      u32t* __restrict__ attTp)
{
    int i = blockIdx.x * 256 + threadIdx.x;
    if (i >= NN * 2 * 32 * 16) return;
    int e = i & 15;
    int r = i >> 4;                 // (n*2+s)*32 + v
    int v = r & 31;
    int ns = r >> 5;
    int s = ns & 1;
    if (v >= 27) { attTp[i] = 0u; return; }
    const float* sb = scores + ns * 729;
    const float* ab = att0 + s * 729;
    float al = alphas[s];
    int u0 = 2 * e, u1 = 2 * e + 1;
    float a0 = (u0 < 27) ? tanhf(sb[u0 * 27 + v] * (1.f / 6400.f)) * al + ab[u0 * 27 + v] : 0.f;
    float a1 = (u1 < 27) ? tanhf(sb[u1 * 27 + v] * (1.f / 6400.f)) * al + ab[u1 * 27 + v] : 0.f;
    attTp[i] = packbf(a0, a1);
}

// ---------------------------------------------------------------------------
// k_stage1 (MFMA, 8 waves): per (n, 4-t chunk). p = tt*28+v (112 px).
//   xs[tt][c][32u] bf16, u-block XOR-swizzled by (c>>1)&3 (2-way banks).
//   mm  : wave (t = w&3, s = w>>2): 8 mfma -> mmL[p][j-pair]
//   fold: wave (ot = w&3, h = w>>2): o-rows ot*16.., N-half h -> y1L
//   ff  : same split -> y2T[n][pixel][c] via uint2 stores (transposed!)
// ---------------------------------------------------------------------------
__global__ __launch_bounds__(512, 4) void k_stage1(
    const float* __restrict__ x, const u32t* __restrict__ attTp,
    const u16t* __restrict__ wfoA, const float* __restrict__ bfo,
    const u16t* __restrict__ wffA, const float* __restrict__ bff,
    u16t* __restrict__ y2T)
{
    const int tid = threadIdx.x;
    const int n = blockIdx.y, t0 = blockIdx.x * TB1;
    const int w = tid >> 6, li = tid & 15, g = (tid >> 4) & 3;

    __shared__ __align__(16) u16t xs[4 * 64 * 32];        // 16384 B [tt][c][32u swz]
    __shared__ __align__(16) u32t mmL[112 * 68];          // 30464 B [p][j-pair]
    __shared__ __align__(16) u32t y1L[112 * 34];          // 15232 B [p][c-pair]

    // staging: u32-pair writes, swizzled u-block
    for (int j = tid; j < 4096; j += 512) {
        int i = j & 15, c = (j >> 4) & 63, tt = j >> 10;
        const float* xrow = x + (size_t)(n * 64 + c) * PIX + (size_t)(t0 + tt) * 27;
        int u0 = 2 * i;
        float v0 = (u0 < 27) ? xrow[u0] : 0.f;
        float v1 = (u0 + 1 < 27) ? xrow[u0 + 1] : 0.f;
        int ip = i ^ (((c >> 1) & 3) << 2);
        reinterpret_cast<u32t*>(xs)[(tt * 64 + c) * 16 + ip] = packbf(v0, v1);
    }
    __syncthreads();

    // ---- mm: wave (t, s) ----
    {
        const int t = w & 3, s = w >> 2;
        bf16x8 ax[4];
        #pragma unroll
        for (int Mt = 0; Mt < 4; ++Mt) {
            const int c = Mt * 16 + li;
            const int blk = g ^ ((li >> 1) & 3);
            ax[Mt] = *reinterpret_cast<const bf16x8*>(&xs[(t * 64 + c) * 32 + blk * 8]);
        }
        const u16t* attp16 = reinterpret_cast<const u16t*>(attTp);
        #pragma unroll
        for (int Nt = 0; Nt < 2; ++Nt) {
            bf16x8 b = *reinterpret_cast<const bf16x8*>(
                &attp16[(((n * 2 + s) * 32) + Nt * 16 + li) * 32 + g * 8]);
            const int v = Nt * 16 + li;
            #pragma unroll
            for (int Mt = 0; Mt < 4; ++Mt) {
                f32x4 d = {0.f, 0.f, 0.f, 0.f};
                d = __builtin_amdgcn_mfma_f32_16x16x32_bf16(ax[Mt], b, d, 0, 0, 0);
                if (v < 28) {
                    const int p = t * 28 + v;
                    const int j2 = s * 32 + Mt * 8 + g * 2;
                    mmL[p * 68 + j2]     = packbf(d[0], d[1]);
                    mmL[p * 68 + j2 + 1] = packbf(d[2], d[3]);
                }
            }
        }
    }
    __syncthreads();

    const int ot = w & 3, hh = w >> 2;
    const int o0 = ot * 16 + g * 4;

    // ---- fold: wave (ot, hh) ----
    {
        bf16x8 aw[4];
        #pragma unroll
        for (int Ks = 0; Ks < 4; ++Ks)
            aw[Ks] = *reinterpret_cast<const bf16x8*>(&wfoA[(ot * 16 + li) * 128 + Ks * 32 + g * 8]);
        float4 bf4 = ld4(&bfo[o0]);
        #pragma unroll
        for (int q = 0; q < 4; ++q) {
            const int Nt = hh * 4 + q;
            if (Nt >= 7) continue;
            f32x4 d = {0.f, 0.f, 0.f, 0.f};
            #pragma unroll
            for (int Ks = 0; Ks < 4; ++Ks) {
                bf16x8 b = *reinterpret_cast<const bf16x8*>(&mmL[(Nt * 16 + li) * 68 + Ks * 16 + g * 4]);
                d = __builtin_amdgcn_mfma_f32_16x16x32_bf16(aw[Ks], b, d, 0, 0, 0);
            }
            const int p = Nt * 16 + li;
            const int tt = p / 28, v = p - tt * 28;
            const int sw0 = ((o0 >> 1) & 3) << 3;        // o0, o0+1 share o>>1
            const int sw1 = (((o0 + 2) >> 1) & 3) << 3;  // o0+2, o0+3
            float ya = lrelu(bf2f(xs[(tt * 64 + o0 + 0) * 32 + (v ^ sw0)]) + d[0] + bf4.x);
            float yb = lrelu(bf2f(xs[(tt * 64 + o0 + 1) * 32 + (v ^ sw0)]) + d[1] + bf4.y);
            float yc = lrelu(bf2f(xs[(tt * 64 + o0 + 2) * 32 + (v ^ sw1)]) + d[2] + bf4.z);
            float yd = lrelu(bf2f(xs[(tt * 64 + o0 + 3) * 32 + (v ^ sw1)]) + d[3] + bf4.w);
            y1L[p * 34 + ot * 8 + g * 2]     = packbf(ya, yb);
            y1L[p * 34 + ot * 8 + g * 2 + 1] = packbf(yc, yd);
        }
    }
    __syncthreads();

    // ---- ff: wave (ot, hh) -> y2T[n][pixel][c], uint2 per lane ----
    {
        bf16x8 af[2];
        #pragma unroll
        for (int Ks = 0; Ks < 2; ++Ks)
            af[Ks] = *reinterpret_cast<const bf16x8*>(&wffA[(ot * 16 + li) * 64 + Ks * 32 + g * 8]);
        float4 bff4 = ld4(&bff[o0]);
        #pragma unroll
        for (int q = 0; q < 4; ++q) {
            const int Nt = hh * 4 + q;
            if (Nt >= 7) continue;
            f32x4 d = {0.f, 0.f, 0.f, 0.f};
            #pragma unroll
            for (int Ks = 0; Ks < 2; ++Ks) {
                union { uint2 u2[2]; bf16x8 v8; } bu;
                bu.u2[0] = *reinterpret_cast<const uint2*>(&y1L[(Nt * 16 + li) * 34 + Ks * 16 + g * 4]);
                bu.u2[1] = *reinterpret_cast<const uint2*>(&y1L[(Nt * 16 + li) * 34 + Ks * 16 + g * 4 + 2]);
                d = __builtin_amdgcn_mfma_f32_16x16x32_bf16(af[Ks], bu.v8, d, 0, 0, 0);
            }
            const int p = Nt * 16 + li;
            const int tt = p / 28, v = p - tt * 28;
            if (v < 27) {
                const int sw0 = ((o0 >> 1) & 3) << 3;
                const int sw1 = (((o0 + 2) >> 1) & 3) << 3;
                float r0 = lrelu(bf2f(xs[(tt * 64 + o0 + 0) * 32 + (v ^ sw0)]) + d[0] + bff4.x);
                float r1 = lrelu(bf2f(xs[(tt * 64 + o0 + 1) * 32 + (v ^ sw0)]) + d[1] + bff4.y);
                float r2 = lrelu(bf2f(xs[(tt * 64 + o0 + 2) * 32 + (v ^ sw1)]) + d[2] + bff4.z);
                float r3 = lrelu(bf2f(xs[(tt * 64 + o0 + 3) * 32 + (v ^ sw1)]) + d[3] + bff4.w);
                uint2 st;
                st.x = packbf(r0, r1);
                st.y = packbf(r2, r3);
                size_t P = (size_t)n * PIX + (size_t)(t0 + tt) * 27 + v;
                *reinterpret_cast<uint2*>(y2T + P * 64 + o0) = st;
            }
        }
    }
}

// ---------------------------------------------------------------------------
// k_stage2 (MFMA, LDS-free): per (n, 4-t chunk). p = tt*28+v (112 px).
//   out[o][t][v] = lrelu(y2T[t*27+v][o] + mfma(WtA, B) + bft)
//   B-fragments: direct 16B global loads from y2T[pixel][c] (k' = kt*64+c).
//   Zero-select for t out of range / v==27 pad columns.
// ---------------------------------------------------------------------------
__global__ __launch_bounds__(256, 8) void k_stage2(
    const u16t* __restrict__ y2T, const u16t* __restrict__ wtA,
    const float* __restrict__ bft, float* __restrict__ out)
{
    const int tid = threadIdx.x;
    const int n = blockIdx.y, t0 = blockIdx.x * TB2;
    const int w = tid >> 6, li = tid & 15, g = (tid >> 4) & 3;
    const int o0 = w * 16 + g * 4;

    const u16t* yb = y2T + (size_t)n * PIX * 64;

    bf16x8 aw[6];
    #pragma unroll
    for (int Ks = 0; Ks < 6; ++Ks)
        aw[Ks] = *reinterpret_cast<const bf16x8*>(&wtA[(w * 16 + li) * 192 + Ks * 32 + g * 8]);
    float4 bt4 = ld4(&bft[o0]);
    const bf16x8 bz = {0, 0, 0, 0, 0, 0, 0, 0};

    #pragma unroll
    for (int Nt = 0; Nt < 7; ++Nt) {
        const int p = Nt * 16 + li;
        const int tt = p / 28, v = p - tt * 28;
        const int vc = v < 27 ? v : 26;
        f32x4 d = {0.f, 0.f, 0.f, 0.f};
        #pragma unroll
        for (int Ks = 0; Ks < 6; ++Ks) {
            const int kt = Ks >> 1, c0 = (Ks & 1) * 32 + g * 8;
            const int tk = t0 + tt + kt - 1;
            const bool ok = (v < 27) && (tk >= 0) && (tk < TT);
            const int tkc = tk < 0 ? 0 : (tk >= TT ? TT - 1 : tk);
            bf16x8 b = *reinterpret_cast<const bf16x8*>(&yb[((size_t)tkc * 27 + vc) * 64 + c0]);
            b = ok ? b : bz;
            d = __builtin_amdgcn_mfma_f32_16x16x32_bf16(aw[Ks], b, d, 0, 0, 0);
        }
        if (v < 27) {
            const size_t Pq = (size_t)(t0 + tt) * 27 + v;
            uint2 rv = *reinterpret_cast<const uint2*>(&yb[Pq * 64 + o0]);
            float* ob = out + (size_t)(n * 64) * PIX + Pq;
            ob[(size_t)(o0 + 0) * PIX] = lrelu(bf2f((u16t)(rv.x & 0xffff)) + d[0] + bt4.x);
            ob[(size_t)(o0 + 1) * PIX] = lrelu(bf2f((u16t)(rv.x >> 16))    + d[1] + bt4.y);
            ob[(size_t)(o0 + 2) * PIX] = lrelu(bf2f((u16t)(rv.y & 0xffff)) + d[2] + bt4.z);
            ob[(size_t)(o0 + 3) * PIX] = lrelu(bf2f((u16t)(rv.y >> 16))    + d[3] + bt4.w);
        }
    }
}

// ---------------------------------------------------------------------------
extern "C" void kernel_launch(void* const* d_in, const int* in_sizes, int n_in,
                              void* d_out, int out_size, void* d_ws, size_t ws_size,
                              hipStream_t stream)
{
    const float* x      = (const float*)d_in[0];
    const float* w_in   = (const float*)d_in[1];
    const float* b_in   = (const float*)d_in[2];
    const float* alphas = (const float*)d_in[3];
    const float* att0   = (const float*)d_in[4];
    const float* w_outs = (const float*)d_in[5];
    const float* b_outs = (const float*)d_in[6];
    const float* bog    = (const float*)d_in[7];
    const float* bob    = (const float*)d_in[8];
    const float* bom    = (const float*)d_in[9];
    const float* bov    = (const float*)d_in[10];
    const float* w_ff   = (const float*)d_in[11];
    const float* b_ff   = (const float*)d_in[12];
    const float* bfg    = (const float*)d_in[13];
    const float* bfb    = (const float*)d_in[14];
    const float* bfm    = (const float*)d_in[15];
    const float* bfv    = (const float*)d_in[16];
    const float* w_t    = (const float*)d_in[17];
    const float* b_t    = (const float*)d_in[18];
    const float* btg    = (const float*)d_in[19];
    const float* btb    = (const float*)d_in[20];
    const float* btm    = (const float*)d_in[21];
    const float* btv    = (const float*)d_in[22];

    // ws layout (u32 units):
    // pb 1792 | scores 46656 | attTp 32768 | wfoA 4096 | wffA 2048 |
    // wtA 6144 | bfo 64 | bff 64 | bft 64 | wqkpk 2048 | y2T (u16 XTOT)
    float* pbw    = (float*)d_ws;
    float* scores = pbw + 1792;
    u32t*  attTp  = (u32t*)(scores + NSUV);
    u16t*  wfoA   = (u16t*)(attTp + 32768);
    u16t*  wffA   = (u16t*)((u32t*)wfoA + 4096);
    u16t*  wtA    = (u16t*)((u32t*)wffA + 2048);
    float* bfo    = (float*)((u32t*)wtA + 6144);
    float* bff    = bfo + 64;
    float* bft    = bff + 64;
    u32t*  wqkpk  = (u32t*)(bft + 64);
    u16t*  y2T    = (u16t*)(wqkpk + 2048);

    hipMemsetAsync(scores, 0, NSUV * sizeof(float), stream);

    k_prep<<<32, 256, 0, stream>>>(w_outs, b_outs, bog, bob, bom, bov,
                                   w_ff, b_ff, bfg, bfb, bfm, bfv,
                                   w_t, b_t, btg, btb, btm, btv, w_in,
                                   wfoA, bfo, wffA, bff, wtA, bft, wqkpk);
    k_pbias<<<1, 256, 0, stream>>>(w_in, b_in, pbw);
    k_scores<<<dim3(NTS, 2, NN), 256, 0, stream>>>(x, wqkpk, pbw, scores);
    k_att<<<(NN * 2 * 32 * 16 + 255) / 256, 256, 0, stream>>>(scores, alphas, att0, attTp);
    k_stage1<<<dim3(NT1, NN), 512, 0, stream>>>(x, attTp, wfoA, bfo, wffA, bff, y2T);
    k_stage2<<<dim3(NT2, NN), 256, 0, stream>>>(y2T, wtA, bft, (float*)d_out);
}

// Round 11
// 355.163 us; speedup vs baseline: 1.2213x; 1.2213x over previous
//
#include <hip/hip_runtime.h>
#include <hip/hip_bf16.h>
#include <math.h>

// STAttentionBlock  N=32 C=64 T=400 V=27 S=2 IC=16 — f32 I/O.
// Round 14: stage2 = round-11 LDS-tile MFMA body (verified), but staged from
// the transposed y2T[n][pixel][c] with coalesced uint4 loads (1296 vec loads
// vs 10.7K scalar u16 in round 11; vs round-13's LDS-free variant that
// thrashed L2: FETCH 116MB, WRITE 197MB). stage1 = round-13 (y2T uint2 ff
// writes, verified). k_scores = round 7.

typedef __hip_bfloat16 bf16;
typedef unsigned short u16t;
typedef unsigned int u32t;

using bf16x8 = __attribute__((ext_vector_type(8))) short;
using f32x4  = __attribute__((ext_vector_type(4))) float;

#define NN 32
#define CH 64
#define TT 400
#define VV 27
#define PIX 10800            // T*V
#define NSUV (32*2*27*27)    // 46656
#define XTOT (NN*CH*PIX)     // 22118400

#define TB1 4                // t per block, stage1 (112 pixels = 7 tiles of 16)
#define NT1 100
#define TB2 4                // t per block, stage2 (MFMA)
#define NT2 100
#define TBS 9                // t per block, scores
#define NTS 45

__device__ __forceinline__ float lrelu(float x) { return x >= 0.f ? x : 0.1f * x; }
__device__ __forceinline__ float4 ld4(const float* p) { return *reinterpret_cast<const float4*>(p); }
__device__ __forceinline__ uint2 ld2u(const u32t* p) { return *reinterpret_cast<const uint2*>(p); }

// packed bf16 helpers
__device__ __forceinline__ u16t f2bf(float f) {
    return __bfloat16_as_ushort(__float2bfloat16(f));
}
__device__ __forceinline__ u32t packbf(float lo, float hi) {
    return ((u32t)f2bf(hi) << 16) | (u32t)f2bf(lo);
}
__device__ __forceinline__ float bf2f(u16t u) {
    return __uint_as_float(((u32t)u) << 16);
}
__device__ __forceinline__ u32t cvtpk(float lo, float hi) {
    u32t r;
    asm("v_cvt_pk_bf16_f32 %0, %1, %2" : "=v"(r) : "v"(lo), "v"(hi));
    return r;
}
// c += a.lo*b.lo + a.hi*b.hi  (bf16 pairs, f32 accum)
__device__ __forceinline__ void dot2v(float& c, u32t a, u32t b) {
    asm("v_dot2_f32_bf16 %0, %1, %2, %0" : "+v"(c) : "v"(a), "v"(b));
}
__device__ __forceinline__ void dot2s(float& c, u32t a_sgpr, u32t b) {
    asm("v_dot2_f32_bf16 %0, %1, %2, %0" : "+v"(c) : "s"(a_sgpr), "v"(b));
}

// ---------------------------------------------------------------------------
// k_prep: BN-folded weights.
//   wfoA[o*128+j]        bf16 row-major (j = s*64+c)   conv_outs A-operand
//   wffA[o*64+c]         bf16 row-major                ff A-operand
//   wtA [o*192+kt*64+c]  bf16 row-major (k' kt-major)  tconv A-operand
//   wqkpk[(sq*16+c)*32+cc2] u32 pairs                  scores proj
//   bfo/bff/bft[o] = b*inv + beta
// ---------------------------------------------------------------------------
__global__ void k_prep(
    const float* __restrict__ w_outs, const float* __restrict__ b_outs,
    const float* __restrict__ go, const float* __restrict__ bo,
    const float* __restrict__ mo, const float* __restrict__ vo,
    const float* __restrict__ w_ff, const float* __restrict__ b_ff,
    const float* __restrict__ gf, const float* __restrict__ bf,
    const float* __restrict__ mf, const float* __restrict__ vf,
    const float* __restrict__ w_t, const float* __restrict__ b_t,
    const float* __restrict__ gt, const float* __restrict__ btb,
    const float* __restrict__ mt, const float* __restrict__ vt,
    const float* __restrict__ w_in,
    u16t* __restrict__ wfoA, float* __restrict__ bfo,
    u16t* __restrict__ wffA, float* __restrict__ bff,
    u16t* __restrict__ wtA, float* __restrict__ bft,
    u32t* __restrict__ wqkpk)
{
    const int total = 8192 + 4096 + 12288 + 192 + 2048;
    for (int idx = blockIdx.x * 256 + threadIdx.x; idx < total; idx += gridDim.x * 256) {
        if (idx < 8192) {
            int o = idx >> 7, j = idx & 127;
            float inv = go[o] * rsqrtf(vo[o] + 1e-5f);
            wfoA[idx] = f2bf(w_outs[o * 128 + j] * inv);
        } else if (idx < 12288) {
            int r = idx - 8192; int o = r >> 6, c = r & 63;
            float inv = gf[o] * rsqrtf(vf[o] + 1e-5f);
            wffA[r] = f2bf(w_ff[o * 64 + c] * inv);
        } else if (idx < 24576) {
            int r = idx - 12288;                  // r = o*192 + kt*64 + c
            int o = r / 192, k2 = r % 192;
            int kt = k2 >> 6, c = k2 & 63;
            float inv = gt[o] * rsqrtf(vt[o] + 1e-5f);
            wtA[r] = f2bf(w_t[o * 192 + c * 3 + kt] * inv);
        } else if (idx < 24768) {
            int r = idx - 24576; int o = r & 63, which = r >> 6;
            if (which == 0) {
                float inv = go[o] * rsqrtf(vo[o] + 1e-5f);
                bfo[o] = b_outs[o] * inv + bo[o] - mo[o] * inv;
            } else if (which == 1) {
                float inv = gf[o] * rsqrtf(vf[o] + 1e-5f);
                bff[o] = b_ff[o] * inv + bf[o] - mf[o] * inv;
            } else {
                float inv = gt[o] * rsqrtf(vt[o] + 1e-5f);
                bft[o] = b_t[o] * inv + btb[o] - mt[o] * inv;
            }
        } else {
            int i = idx - 24768;                 // i < 2048
            int cc2 = i & 31, c = (i >> 5) & 15, sq = i >> 9;
            int s = sq >> 1, qk = sq & 1;
            int row = qk * 32 + s * 16 + c;
            wqkpk[i] = packbf(w_in[row * 64 + 2 * cc2], w_in[row * 64 + 2 * cc2 + 1]);
        }
    }
}

// ---------------------------------------------------------------------------
// k_pbias: pb[s*2+qk][c][u28] = b_in + sum_cc w_in * pe[cc][u]  (PE absorbed)
// ---------------------------------------------------------------------------
__global__ __launch_bounds__(256) void k_pbias(
    const float* __restrict__ w_in, const float* __restrict__ b_in,
    float* __restrict__ pb)
{
    __shared__ float pe[64 * 27];
    const int tid = threadIdx.x;
    for (int idx = tid; idx < 1728; idx += 256) {
        int c = idx / 27, u = idx % 27;
        float div = expf(-0.28782313662425575f * (float)(c >> 1));
        float ang = div * (float)u;
        pe[idx] = (c & 1) ? cosf(ang) : sinf(ang);
    }
    __syncthreads();
    for (int idx = tid; idx < 1792; idx += 256) {
        int u = idx % 28, r = idx / 28;
        int c = r % 16, sq = r / 16;
        if (u >= 27) { pb[idx] = 0.f; continue; }
        int s = sq >> 1, qk = sq & 1;
        int row = qk * 32 + s * 16 + c;
        float acc = b_in[row];
        for (int cc = 0; cc < 64; ++cc) acc += w_in[row * 64 + cc] * pe[cc * 27 + u];
        pb[idx] = acc;
    }
}

// ---------------------------------------------------------------------------
// k_scores: grid (45 tchunks, 2 s, 32 n). Lane = pixel (tt,u). (round 7)
// ---------------------------------------------------------------------------
__global__ __launch_bounds__(256, 4) void k_scores(
    const float* __restrict__ x, const u32t* __restrict__ wqkpk,
    const float* __restrict__ pb, float* __restrict__ scores)
{
    const int tid = threadIdx.x;
    const int s = blockIdx.y, n = blockIdx.z;
    const int t0 = blockIdx.x * TBS;

    __shared__ u32t qlds[TBS * 27 * 10];
    __shared__ u32t klds[TBS * 27 * 10];

    const int pcl = tid < 243 ? tid : 242;
    const int tt = pcl / 27, u = pcl - tt * 27;
    const int t = t0 + tt;
    const bool valid = (tid < 243) && (t < TT);

    u32t xp[32];
    const float* xb = x + (size_t)n * 64 * PIX + (size_t)(t < TT ? t : 0) * 27 + u;
    #pragma unroll
    for (int c2 = 0; c2 < 32; ++c2) {
        float v0 = xb[(size_t)(2 * c2) * PIX];
        float v1 = xb[(size_t)(2 * c2 + 1) * PIX];
        xp[c2] = cvtpk(v0, v1);
    }

    const float* pbq = pb + ((s * 2 + 0) * 16) * 28 + u;
    const float* pbk = pb + ((s * 2 + 1) * 16) * 28 + u;
    const u32t* wq = wqkpk + (s * 2 + 0) * 16 * 32;
    const u32t* wk = wqkpk + (s * 2 + 1) * 16 * 32;
    float qr[16], kr[16];
    #pragma unroll
    for (int c = 0; c < 16; ++c) { qr[c] = pbq[c * 28]; kr[c] = pbk[c * 28]; }
    #pragma unroll
    for (int c = 0; c < 16; ++c) {
        const u32t* wr = wq + c * 32;
        #pragma unroll
        for (int c2 = 0; c2 < 32; ++c2) dot2s(qr[c], wr[c2], xp[c2]);
    }
    #pragma unroll
    for (int c = 0; c < 16; ++c) {
        const u32t* wr = wk + c * 32;
        #pragma unroll
        for (int c2 = 0; c2 < 32; ++c2) dot2s(kr[c], wr[c2], xp[c2]);
    }

    if (tid < 243) {
        #pragma unroll
        for (int c2 = 0; c2 < 8; ++c2) {
            qlds[(tt * 27 + u) * 10 + c2] = valid ? cvtpk(qr[2 * c2], qr[2 * c2 + 1]) : 0u;
            klds[(tt * 27 + u) * 10 + c2] = valid ? cvtpk(kr[2 * c2], kr[2 * c2 + 1]) : 0u;
        }
    }
    __syncthreads();

    const int sid = tid < 243 ? tid : 242;
    const int ug = sid / 9, vg = sid % 9;
    const int v0 = vg * 3;
    float sc0 = 0.f, sc1 = 0.f, sc2 = 0.f;
    for (int t2 = 0; t2 < TBS; ++t2) {
        const u32t* qrow = qlds + (t2 * 27 + ug) * 10;
        const u32t* k0 = klds + (t2 * 27 + v0) * 10;
        #pragma unroll
        for (int c4 = 0; c4 < 4; ++c4) {
            uint2 qp = ld2u(qrow + c4 * 2);
            uint2 ka = ld2u(k0 + c4 * 2);
            uint2 kb = ld2u(k0 + 10 + c4 * 2);
            uint2 kc = ld2u(k0 + 20 + c4 * 2);
            dot2v(sc0, qp.x, ka.x); dot2v(sc0, qp.y, ka.y);
            dot2v(sc1, qp.x, kb.x); dot2v(sc1, qp.y, kb.y);
            dot2v(sc2, qp.x, kc.x); dot2v(sc2, qp.y, kc.y);
        }
    }
    if (tid < 243) {
        float* sb = scores + (n * 2 + s) * 729 + ug * 27 + v0;
        atomicAdd(&sb[0], sc0);
        atomicAdd(&sb[1], sc1);
        atomicAdd(&sb[2], sc2);
    }
}

// ---------------------------------------------------------------------------
// k_att: attTp[((n*2+s)*32+v)*16+e] = pack_bf16(att(2e,v), att(2e+1,v)),
// v-rows 27..31 zero (MFMA B-operand padding).
// ---------------------------------------------------------------------------
__global__ void k_att(const float* __restrict__ scores,
                      const float* __restrict__ alphas,
                      const float* __restrict__ att0,
                      u32t* __restrict__ attTp)
{
    int i = blockIdx.x * 256 + threadIdx.x;
    if (i >= NN * 2 * 32 * 16) return;
    int e = i & 15;
    int r = i >> 4;                 // (n*2+s)*32 + v
    int v = r & 31;
    int ns = r >> 5;
    int s = ns & 1;
    if (v >= 27) { attTp[i] = 0u; return; }
    const float* sb = scores + ns * 729;
    const float* ab = att0 + s * 729;
    float al = alphas[s];
    int u0 = 2 * e, u1 = 2 * e + 1;
    float a0 = (u0 < 27) ? tanhf(sb[u0 * 27 + v] * (1.f / 6400.f)) * al + ab[u0 * 27 + v] : 0.f;
    float a1 = (u1 < 27) ? tanhf(sb[u1 * 27 + v] * (1.f / 6400.f)) * al + ab[u1 * 27 + v] : 0.f;
    attTp[i] = packbf(a0, a1);
}

// ---------------------------------------------------------------------------
// k_stage1 (MFMA, 8 waves): per (n, 4-t chunk). p = tt*28+v (112 px).
//   xs[tt][c][32u] bf16, u-block XOR-swizzled by (c>>1)&3 (2-way banks).
//   mm  : wave (t = w&3, s = w>>2): 8 mfma -> mmL[p][j-pair]
//   fold: wave (ot = w&3, h = w>>2): o-rows ot*16.., N-half h -> y1L
//   ff  : same split -> y2T[n][pixel][c] via uint2 stores (transposed)
// ---------------------------------------------------------------------------
__global__ __launch_bounds__(512, 4) void k_stage1(
    const float* __restrict__ x, const u32t* __restrict__ attTp,
    const u16t* __restrict__ wfoA, const float* __restrict__ bfo,
    const u16t* __restrict__ wffA, const float* __restrict__ bff,
    u16t* __restrict__ y2T)
{
    const int tid = threadIdx.x;
    const int n = blockIdx.y, t0 = blockIdx.x * TB1;
    const int w = tid >> 6, li = tid & 15, g = (tid >> 4) & 3;

    __shared__ __align__(16) u16t xs[4 * 64 * 32];        // 16384 B [tt][c][32u swz]
    __shared__ __align__(16) u32t mmL[112 * 68];          // 30464 B [p][j-pair]
    __shared__ __align__(16) u32t y1L[112 * 34];          // 15232 B [p][c-pair]

    // staging: u32-pair writes, swizzled u-block
    for (int j = tid; j < 4096; j += 512) {
        int i = j & 15, c = (j >> 4) & 63, tt = j >> 10;
        const float* xrow = x + (size_t)(n * 64 + c) * PIX + (size_t)(t0 + tt) * 27;
        int u0 = 2 * i;
        float v0 = (u0 < 27) ? xrow[u0] : 0.f;
        float v1 = (u0 + 1 < 27) ? xrow[u0 + 1] : 0.f;
        int ip = i ^ (((c >> 1) & 3) << 2);
        reinterpret_cast<u32t*>(xs)[(tt * 64 + c) * 16 + ip] = packbf(v0, v1);
    }
    __syncthreads();

    // ---- mm: wave (t, s) ----
    {
        const int t = w & 3, s = w >> 2;
        bf16x8 ax[4];
        #pragma unroll
        for (int Mt = 0; Mt < 4; ++Mt) {
            const int c = Mt * 16 + li;
            const int blk = g ^ ((li >> 1) & 3);
            ax[Mt] = *reinterpret_cast<const bf16x8*>(&xs[(t * 64 + c) * 32 + blk * 8]);
        }
        const u16t* attp16 = reinterpret_cast<const u16t*>(attTp);
        #pragma unroll
        for (int Nt = 0; Nt < 2; ++Nt) {
            bf16x8 b = *reinterpret_cast<const bf16x8*>(
                &attp16[(((n * 2 + s) * 32) + Nt * 16 + li) * 32 + g * 8]);
            const int v = Nt * 16 + li;
            #pragma unroll
            for (int Mt = 0; Mt < 4; ++Mt) {
                f32x4 d = {0.f, 0.f, 0.f, 0.f};
                d = __builtin_amdgcn_mfma_f32_16x16x32_bf16(ax[Mt], b, d, 0, 0, 0);
                if (v < 28) {
                    const int p = t * 28 + v;
                    const int j2 = s * 32 + Mt * 8 + g * 2;
                    mmL[p * 68 + j2]     = packbf(d[0], d[1]);
                    mmL[p * 68 + j2 + 1] = packbf(d[2], d[3]);
                }
            }
        }
    }
    __syncthreads();

    const int ot = w & 3, hh = w >> 2;
    const int o0 = ot * 16 + g * 4;

    // ---- fold: wave (ot, hh) ----
    {
        bf16x8 aw[4];
        #pragma unroll
        for (int Ks = 0; Ks < 4; ++Ks)
            aw[Ks] = *reinterpret_cast<const bf16x8*>(&wfoA[(ot * 16 + li) * 128 + Ks * 32 + g * 8]);
        float4 bf4 = ld4(&bfo[o0]);
        #pragma unroll
        for (int q = 0; q < 4; ++q) {
            const int Nt = hh * 4 + q;
            if (Nt >= 7) continue;
            f32x4 d = {0.f, 0.f, 0.f, 0.f};
            #pragma unroll
            for (int Ks = 0; Ks < 4; ++Ks) {
                bf16x8 b = *reinterpret_cast<const bf16x8*>(&mmL[(Nt * 16 + li) * 68 + Ks * 16 + g * 4]);
                d = __builtin_amdgcn_mfma_f32_16x16x32_bf16(aw[Ks], b, d, 0, 0, 0);
            }
            const int p = Nt * 16 + li;
            const int tt = p / 28, v = p - tt * 28;
            const int sw0 = ((o0 >> 1) & 3) << 3;        // o0, o0+1 share o>>1
            const int sw1 = (((o0 + 2) >> 1) & 3) << 3;  // o0+2, o0+3
            float ya = lrelu(bf2f(xs[(tt * 64 + o0 + 0) * 32 + (v ^ sw0)]) + d[0] + bf4.x);
            float yb = lrelu(bf2f(xs[(tt * 64 + o0 + 1) * 32 + (v ^ sw0)]) + d[1] + bf4.y);
            float yc = lrelu(bf2f(xs[(tt * 64 + o0 + 2) * 32 + (v ^ sw1)]) + d[2] + bf4.z);
            float yd = lrelu(bf2f(xs[(tt * 64 + o0 + 3) * 32 + (v ^ sw1)]) + d[3] + bf4.w);
            y1L[p * 34 + ot * 8 + g * 2]     = packbf(ya, yb);
            y1L[p * 34 + ot * 8 + g * 2 + 1] = packbf(yc, yd);
        }
    }
    __syncthreads();

    // ---- ff: wave (ot, hh) -> y2T[n][pixel][c], uint2 per lane ----
    {
        bf16x8 af[2];
        #pragma unroll
        for (int Ks = 0; Ks < 2; ++Ks)
            af[Ks] = *reinterpret_cast<const bf16x8*>(&wffA[(ot * 16 + li) * 64 + Ks * 32 + g * 8]);
        float4 bff4 = ld4(&bff[o0]);
        #pragma unroll
        for (int q = 0; q < 4; ++q) {
            const int Nt = hh * 4 + q;
            if (Nt >= 7) continue;
            f32x4 d = {0.f, 0.f, 0.f, 0.f};
            #pragma unroll
            for (int Ks = 0; Ks < 2; ++Ks) {
                union { uint2 u2[2]; bf16x8 v8; } bu;
                bu.u2[0] = *reinterpret_cast<const uint2*>(&y1L[(Nt * 16 + li) * 34 + Ks * 16 + g * 4]);
                bu.u2[1] = *reinterpret_cast<const uint2*>(&y1L[(Nt * 16 + li) * 34 + Ks * 16 + g * 4 + 2]);
                d = __builtin_amdgcn_mfma_f32_16x16x32_bf16(af[Ks], bu.v8, d, 0, 0, 0);
            }
            const int p = Nt * 16 + li;
            const int tt = p / 28, v = p - tt * 28;
            if (v < 27) {
                const int sw0 = ((o0 >> 1) & 3) << 3;
                const int sw1 = (((o0 + 2) >> 1) & 3) << 3;
                float r0 = lrelu(bf2f(xs[(tt * 64 + o0 + 0) * 32 + (v ^ sw0)]) + d[0] + bff4.x);
                float r1 = lrelu(bf2f(xs[(tt * 64 + o0 + 1) * 32 + (v ^ sw0)]) + d[1] + bff4.y);
                float r2 = lrelu(bf2f(xs[(tt * 64 + o0 + 2) * 32 + (v ^ sw1)]) + d[2] + bff4.z);
                float r3 = lrelu(bf2f(xs[(tt * 64 + o0 + 3) * 32 + (v ^ sw1)]) + d[3] + bff4.w);
                uint2 st;
                st.x = packbf(r0, r1);
                st.y = packbf(r2, r3);
                size_t P = (size_t)n * PIX + (size_t)(t0 + tt) * 27 + v;
                *reinterpret_cast<uint2*>(y2T + P * 64 + o0) = st;
            }
        }
    }
}

// ---------------------------------------------------------------------------
// k_stage2 (MFMA, LDS tile staged coalesced from y2T): per (n, 4-t chunk).
//   ys[tp][v][c] stride-72 tile (verified round-11 body); staging is 1296
//   uint4 loads from y2T[pixel][c] (fully coalesced, each byte once).
//   B-frags: k' = kt*64+c contiguous bf16x8. v=27 pad rows zeroed.
// ---------------------------------------------------------------------------
__global__ __launch_bounds__(256, 4) void k_stage2(
    const u16t* __restrict__ y2T, const u16t* __restrict__ wtA,
    const float* __restrict__ bft, float* __restrict__ out)
{
    const int tid = threadIdx.x;
    const int n = blockIdx.y, t0 = blockIdx.x * TB2;
    const int w = tid >> 6, li = tid & 15, g = (tid >> 4) & 3;

    __shared__ __align__(16) u16t ys[6 * 28 * 72];        // 24192 B [tp][v][c]

    // coalesced staging: uint4 = 8 ch per load, 6*27*8 = 1296 loads
    for (int idx = tid; idx < 6 * 27 * 8; idx += 256) {
        int q = idx & 7, r = idx >> 3;
        int v = r % 27, tp = r / 27;
        int t = t0 - 1 + tp;
        uint4 val = {0u, 0u, 0u, 0u};
        if (t >= 0 && t < TT)
            val = *reinterpret_cast<const uint4*>(
                &y2T[((size_t)n * PIX + (size_t)t * 27 + v) * 64 + q * 8]);
        *reinterpret_cast<uint4*>(&ys[(tp * 28 + v) * 72 + q * 8]) = val;
    }
    for (int idx = tid; idx < 6 * 8; idx += 256) {        // zero v=27 pad rows
        int q = idx & 7, tp = idx >> 3;
        uint4 z = {0u, 0u, 0u, 0u};
        *reinterpret_cast<uint4*>(&ys[(tp * 28 + 27) * 72 + q * 8]) = z;
    }
    __syncthreads();

    const int o0 = w * 16 + g * 4;
    bf16x8 aw[6];
    #pragma unroll
    for (int Ks = 0; Ks < 6; ++Ks)
        aw[Ks] = *reinterpret_cast<const bf16x8*>(&wtA[(w * 16 + li) * 192 + Ks * 32 + g * 8]);
    float4 bt4 = ld4(&bft[o0]);

    #pragma unroll
    for (int Nt = 0; Nt < 7; ++Nt) {
        const int p = Nt * 16 + li;
        const int tt = p / 28, v = p - tt * 28;
        f32x4 d = {0.f, 0.f, 0.f, 0.f};
        #pragma unroll
        for (int Ks = 0; Ks < 6; ++Ks) {
            const int kt = Ks >> 1, c0 = (Ks & 1) * 32 + g * 8;
            bf16x8 b = *reinterpret_cast<const bf16x8*>(&ys[((tt + kt) * 28 + v) * 72 + c0]);
            d = __builtin_amdgcn_mfma_f32_16x16x32_bf16(aw[Ks], b, d, 0, 0, 0);
        }
        if (v < 27) {
            float* ob = out + (size_t)(n * 64) * PIX + (size_t)(t0 + tt) * 27 + v;
            float r0 = bf2f(ys[((tt + 1) * 28 + v) * 72 + o0 + 0]);
            float r1 = bf2f(ys[((tt + 1) * 28 + v) * 72 + o0 + 1]);
            float r2 = bf2f(ys[((tt + 1) * 28 + v) * 72 + o0 + 2]);
            float r3 = bf2f(ys[((tt + 1) * 28 + v) * 72 + o0 + 3]);
            ob[(size_t)(o0 + 0) * PIX] = lrelu(r0 + d[0] + bt4.x);
            ob[(size_t)(o0 + 1) * PIX] = lrelu(r1 + d[1] + bt4.y);
            ob[(size_t)(o0 + 2) * PIX] = lrelu(r2 + d[2] + bt4.z);
            ob[(size_t)(o0 + 3) * PIX] = lrelu(r3 + d[3] + bt4.w);
        }
    }
}

// ---------------------------------------------------------------------------
extern "C" void kernel_launch(void* const* d_in, const int* in_sizes, int n_in,
                              void* d_out, int out_size, void* d_ws, size_t ws_size,
                              hipStream_t stream)
{
    const float* x      = (const float*)d_in[0];
    const float* w_in   = (const float*)d_in[1];
    const float* b_in   = (const float*)d_in[2];
    const float* alphas = (const float*)d_in[3];
    const float* att0   = (const float*)d_in[4];
    const float* w_outs = (const float*)d_in[5];
    const float* b_outs = (const float*)d_in[6];
    const float* bog    = (const float*)d_in[7];
    const float* bob    = (const float*)d_in[8];
    const float* bom    = (const float*)d_in[9];
    const float* bov    = (const float*)d_in[10];
    const float* w_ff   = (const float*)d_in[11];
    const float* b_ff   = (const float*)d_in[12];
    const float* bfg    = (const float*)d_in[13];
    const float* bfb    = (const float*)d_in[14];
    const float* bfm    = (const float*)d_in[15];
    const float* bfv    = (const float*)d_in[16];
    const float* w_t    = (const float*)d_in[17];
    const float* b_t    = (const float*)d_in[18];
    const float* btg    = (const float*)d_in[19];
    const float* btb    = (const float*)d_in[20];
    const float* btm    = (const float*)d_in[21];
    const float* btv    = (const float*)d_in[22];

    // ws layout (u32 units):
    // pb 1792 | scores 46656 | attTp 32768 | wfoA 4096 | wffA 2048 |
    // wtA 6144 | bfo 64 | bff 64 | bft 64 | wqkpk 2048 | y2T (u16 XTOT)
    float* pbw    = (float*)d_ws;
    float* scores = pbw + 1792;
    u32t*  attTp  = (u32t*)(scores + NSUV);
    u16t*  wfoA   = (u16t*)(attTp + 32768);
    u16t*  wffA   = (u16t*)((u32t*)wfoA + 4096);
    u16t*  wtA    = (u16t*)((u32t*)wffA + 2048);
    float* bfo    = (float*)((u32t*)wtA + 6144);
    float* bff    = bfo + 64;
    float* bft    = bff + 64;
    u32t*  wqkpk  = (u32t*)(bft + 64);
    u16t*  y2T    = (u16t*)(wqkpk + 2048);

    hipMemsetAsync(scores, 0, NSUV * sizeof(float), stream);

    k_prep<<<32, 256, 0, stream>>>(w_outs, b_outs, bog, bob, bom, bov,
                                   w_ff, b_ff, bfg, bfb, bfm, bfv,
                                   w_t, b_t, btg, btb, btm, btv, w_in,
                                   wfoA, bfo, wffA, bff, wtA, bft, wqkpk);
    k_pbias<<<1, 256, 0, stream>>>(w_in, b_in, pbw);
    k_scores<<<dim3(NTS, 2, NN), 256, 0, stream>>>(x, wqkpk, pbw, scores);
    k_att<<<(NN * 2 * 32 * 16 + 255) / 256, 256, 0, stream>>>(scores, alphas, att0, attTp);
    k_stage1<<<dim3(NT1, NN), 512, 0, stream>>>(x, attTp, wfoA, bfo, wffA, bff, y2T);
    k_stage2<<<dim3(NT2, NN), 256, 0, stream>>>(y2T, wtA, bft, (float*)d_out);
}